// Round 10
// baseline (32.057 us; speedup 1.0000x reference)
//
#include <hip/hip_runtime.h>

// Problem constants (match reference)
constexpr int B_IMG = 8;
constexpr int A_ANCH = 150000;
constexpr int C_CLS = 10;
constexpr int TPB = 256;
constexpr int BA = TPB * 2;                       // 512 anchors per block (2/thread)
constexpr int NBX = (A_ANCH + BA - 1) / BA;       // 293
constexpr int IPG = 4;                            // images per group (per block)
constexpr int NGRP = B_IMG / IPG;                 // 2
constexpr int WPB = TPB / 64;                     // 4 waves/block
constexpr int SEG = NBX * WPB;                    // 1172 wave-partials per image

// ws layout: float att_part[B][SEG], rl_part[B][SEG], np_part[B][SEG]
__global__ __launch_bounds__(TPB) void focal_main(
    const float* __restrict__ attr,   // (B, A, C)
    const float* __restrict__ regr,   // (B, A, 4)
    const float* __restrict__ anch,   // (A, 4)
    const float* __restrict__ ann,    // (B, 14)
    float* __restrict__ att_part,
    float* __restrict__ rl_part,
    float* __restrict__ np_part)
{
    const int g   = blockIdx.y;
    const int b0  = g * IPG;
    const int tid = threadIdx.x;
    const int a0  = (blockIdx.x * TPB + tid) * 2;
    const bool valid = (a0 < A_ANCH);   // A even -> a0 valid => a0+1 valid

    const float TH  = (float)(1.0 / 9.0);
    const float SUB = (float)(0.5 / 9.0);
    const float PHI = (float)(1.0 - 0.0001);

    float att[IPG], rl[IPG], npf[IPG];
#pragma unroll
    for (int i = 0; i < IPG; ++i) { att[i] = 0.0f; rl[i] = 0.0f; npf[i] = 0.0f; }

    if (valid) {
        // ---- anchor geometry: loaded & derived ONCE for all IPG images ----
        const float4* anp = reinterpret_cast<const float4*>(anch) + a0;
        const float4 anA = anp[0];
        const float4 anB = anp[1];
        float ax1[2], ay1[2], aw[2], ah[2], acx[2], acy[2], aarea[2];
        {
            const float4 an[2] = {anA, anB};
#pragma unroll
            for (int k = 0; k < 2; ++k) {
                ax1[k] = an[k].z; ay1[k] = an[k].w;
                aw[k] = an[k].z - an[k].x;
                ah[k] = an[k].w - an[k].y;
                acx[k] = an[k].x + 0.5f * aw[k];
                acy[k] = an[k].y + 0.5f * ah[k];
                aarea[k] = aw[k] * ah[k];
            }
        }
        const float ax0v[2] = {anA.x, anB.x};
        const float ay0v[2] = {anA.y, anB.y};

        const size_t f4row0 = (((size_t)b0 * A_ANCH + a0) * C_CLS) >> 2;  // float4 index, image b0
        const size_t f4stride = ((size_t)A_ANCH * C_CLS) >> 2;            // per-image stride
        const float4* atp = reinterpret_cast<const float4*>(attr);

        float4 bufA[5], bufB[5];
#pragma unroll
        for (int j = 0; j < 5; ++j) bufA[j] = atp[f4row0 + j];            // prefetch image b0

        // per-image body; cur/nxt are statically-bound register buffers (rule #20)
        auto body = [&](const int i, float4 (&cur)[5], float4 (&nxt)[5],
                        const bool prefetch, float& att_i, float& rl_i, float& np_i) {
            const int b = b0 + i;
            if (prefetch) {                     // issue next image's loads first
#pragma unroll
                for (int j = 0; j < 5; ++j) nxt[j] = atp[f4row0 + (size_t)(i + 1) * f4stride + j];
            }
            // annotation: wave-uniform scalar loads
            const float* annb = ann + b * 14;
            const float bx0 = annb[0], by0 = annb[1], bx1 = annb[2], by1 = annb[3];
            float lab[C_CLS];
#pragma unroll
            for (int c = 0; c < C_CLS; ++c) lab[c] = annb[4 + c];

            const float gw_raw = bx1 - bx0;
            const float gh_raw = by1 - by0;
            const float area = gw_raw * gh_raw;
            const float gcx = bx0 + 0.5f * gw_raw;
            const float gcy = by0 + 0.5f * gh_raw;
            const float gw = fmaxf(gw_raw, 1.0f);
            const float gh = fmaxf(gh_raw, 1.0f);

#pragma unroll
            for (int k = 0; k < 2; ++k) {
                float iw = fminf(ax1[k], bx1) - fmaxf(ax0v[k], bx0);
                float ih = fminf(ay1[k], by1) - fmaxf(ay0v[k], by0);
                iw = fmaxf(iw, 0.0f);
                ih = fmaxf(ih, 0.0f);
                const float inter = iw * ih;
                const float uni = fmaxf(aarea[k] + area - inter, 1e-8f);
                const float iou = inter / uni;
                const bool pos = (iou >= 0.5f);
                const bool neg = (iou < 0.4f);

                if (pos || neg) {
#pragma unroll
                    for (int c = 0; c < C_CLS; ++c) {
                        const int e = k * C_CLS + c;
                        const float4& v = cur[e >> 2];
                        const float pe = (e & 3) == 0 ? v.x : (e & 3) == 1 ? v.y
                                       : (e & 3) == 2 ? v.z : v.w;
                        const float p = fminf(fmaxf(pe, 1e-4f), PHI);
                        const float tgt = pos ? lab[c] : 0.0f;
                        float loss;
                        if (tgt == 1.0f) {
                            const float q = 1.0f - p;
                            loss = 0.25f * (q * q) * (-__logf(p));
                        } else {
                            loss = 0.75f * (p * p) * (-__logf(1.0f - p));
                        }
                        att_i += loss;
                    }
                }
                if (pos) {
                    np_i += 1.0f;
                    const float t0 = ((gcx - acx[k]) / aw[k]) / 0.1f;
                    const float t1 = ((gcy - acy[k]) / ah[k]) / 0.1f;
                    const float t2 = __logf(gw / aw[k]) / 0.2f;
                    const float t3 = __logf(gh / ah[k]) / 0.2f;
                    const float4 r = *reinterpret_cast<const float4*>(
                        regr + ((size_t)b * A_ANCH + a0 + k) * 4);
                    float d;
                    d = fabsf(t0 - r.x); rl_i += (d <= TH) ? 4.5f * d * d : d - SUB;
                    d = fabsf(t1 - r.y); rl_i += (d <= TH) ? 4.5f * d * d : d - SUB;
                    d = fabsf(t2 - r.z); rl_i += (d <= TH) ? 4.5f * d * d : d - SUB;
                    d = fabsf(t3 - r.w); rl_i += (d <= TH) ? 4.5f * d * d : d - SUB;
                }
            }
        };

        body(0, bufA, bufB, true,  att[0], rl[0], npf[0]);
        body(1, bufB, bufA, true,  att[1], rl[1], npf[1]);
        body(2, bufA, bufB, true,  att[2], rl[2], npf[2]);
        body(3, bufB, bufA, false, att[3], rl[3], npf[3]);
    }

    // wave (64-lane) reduce of 12 values; lane 0 stores wave partials directly.
#pragma unroll
    for (int off = 32; off > 0; off >>= 1) {
#pragma unroll
        for (int i = 0; i < IPG; ++i) {
            att[i] += __shfl_down(att[i], off);
            rl[i]  += __shfl_down(rl[i], off);
            npf[i] += __shfl_down(npf[i], off);
        }
    }
    const int wave = tid >> 6;
    const int lane = tid & 63;
    if (lane == 0) {
        const int widx = blockIdx.x * WPB + wave;
#pragma unroll
        for (int i = 0; i < IPG; ++i) {
            const int idx = (b0 + i) * SEG + widx;
            att_part[idx] = att[i];
            rl_part[idx]  = rl[i];
            np_part[idx]  = npf[i];
        }
    }
}

// One block, 8 waves: wave b tree-reduces image b's SEG partials.
__global__ __launch_bounds__(512) void focal_finalize(
    const float* __restrict__ att_part,
    const float* __restrict__ rl_part,
    const float* __restrict__ np_part,
    float* __restrict__ out)
{
    const int wave = threadIdx.x >> 6;
    const int lane = threadIdx.x & 63;
    float as = 0.0f, rs = 0.0f, ns = 0.0f;
    if (wave < B_IMG) {
        for (int i = lane; i < SEG; i += 64) {
            as += att_part[wave * SEG + i];
            rs += rl_part[wave * SEG + i];
            ns += np_part[wave * SEG + i];
        }
    }
#pragma unroll
    for (int off = 32; off > 0; off >>= 1) {
        as += __shfl_down(as, off);
        rs += __shfl_down(rs, off);
        ns += __shfl_down(ns, off);
    }
    __shared__ float sa[B_IMG], sr[B_IMG], sn[B_IMG];
    if (lane == 0 && wave < B_IMG) { sa[wave] = as; sr[wave] = rs; sn[wave] = ns; }
    __syncthreads();
    if (threadIdx.x == 0) {
        double am = 0.0, rm = 0.0;
        for (int b = 0; b < B_IMG; ++b) {
            const double npd = (double)sn[b];
            const double den = npd > 0.0 ? npd : 1.0;
            am += (double)sa[b] / den;
            if (npd > 0.0) rm += (double)sr[b] / (den * 4.0);
        }
        out[0] = (float)(am / (double)B_IMG);
        out[1] = (float)(rm / (double)B_IMG);
    }
}

extern "C" void kernel_launch(void* const* d_in, const int* in_sizes, int n_in,
                              void* d_out, int out_size, void* d_ws, size_t ws_size,
                              hipStream_t stream) {
    const float* attr = (const float*)d_in[0];   // attributes (B,A,C)
    const float* regr = (const float*)d_in[1];   // regressions (B,A,4)
    const float* anch = (const float*)d_in[2];   // anchors (1,A,4)
    const float* ann  = (const float*)d_in[3];   // annotations (B,14)
    float* out = (float*)d_out;

    float* att_part = (float*)d_ws;
    float* rl_part  = att_part + B_IMG * SEG;
    float* np_part  = rl_part + B_IMG * SEG;
    // All partials are written unconditionally every launch -> no memset needed.

    dim3 grid(NBX, NGRP);
    focal_main<<<grid, TPB, 0, stream>>>(attr, regr, anch, ann, att_part, rl_part, np_part);
    focal_finalize<<<1, 512, 0, stream>>>(att_part, rl_part, np_part, out);
}

// Round 11
// 27.155 us; speedup vs baseline: 1.1805x; 1.1805x over previous
//
#include <hip/hip_runtime.h>

// Problem constants (match reference)
constexpr int B_IMG = 8;
constexpr int A_ANCH = 150000;
constexpr int C_CLS = 10;
constexpr int TPB = 256;
constexpr int BA = TPB * 2;                       // 512 anchors per block
constexpr int NBX = (A_ANCH + BA - 1) / BA;       // 293
constexpr int F4_PER_IMG = A_ANCH * C_CLS / 4;    // 375000
constexpr int F4_PER_BLK = BA * C_CLS / 4;        // 1280

// ws layout: float att_part[B][NBX], rl_part[B][NBX], np_part[B][NBX]
//
// Coalescing by decoupling float-ownership from anchor-ownership:
//   Phase A: thread owns anchors blk*512+tid and +256 (lane-consecutive float4
//            anchor loads), computes IoU -> 1 flag byte/anchor in LDS
//            (0=ignore, 1=neg, 2=pos) + regression loss for rare pos anchors.
//   Phase B: 5 lane-consecutive attr float4s/thread; per float f: anchor=f/10
//            (magic mul), class=f%10, flag from LDS, focal term.
// Requests/wave: ~448 -> ~112 (4 lanes/line instead of 1).
__global__ __launch_bounds__(TPB) void focal_main(
    const float* __restrict__ attr,   // (B, A, C)
    const float* __restrict__ regr,   // (B, A, 4)
    const float* __restrict__ anch,   // (A, 4)
    const float* __restrict__ ann,    // (B, 14)
    float* __restrict__ att_part,
    float* __restrict__ rl_part,
    float* __restrict__ np_part)
{
    __shared__ unsigned char sFlag[BA];

    const int b   = blockIdx.y;
    const int blk = blockIdx.x;
    const int tid = threadIdx.x;

    // ---- issue ALL coalesced global loads upfront ----
    const float4* atp = reinterpret_cast<const float4*>(attr) + (size_t)b * F4_PER_IMG;
    float4 av[5];
#pragma unroll
    for (int j = 0; j < 5; ++j) {
        int f4 = blk * F4_PER_BLK + j * TPB + tid;
        f4 = (f4 < F4_PER_IMG) ? f4 : (F4_PER_IMG - 1);   // clamp; flags gate correctness
        av[j] = atp[f4];
    }
    const int A0 = blk * BA + tid;
    const int A1 = A0 + TPB;
    const bool v0 = (A0 < A_ANCH);
    const bool v1 = (A1 < A_ANCH);
    const float4* anp = reinterpret_cast<const float4*>(anch);
    const float4 an0 = anp[v0 ? A0 : 0];
    const float4 an1 = anp[v1 ? A1 : 0];

    // annotation (wave-uniform scalar loads)
    const float* annb = ann + b * 14;
    const float bx0 = annb[0], by0 = annb[1], bx1 = annb[2], by1 = annb[3];
    unsigned labmask = 0;
#pragma unroll
    for (int c = 0; c < C_CLS; ++c) labmask |= (annb[4 + c] == 1.0f ? 1u : 0u) << c;

    const float gw_raw = bx1 - bx0;
    const float gh_raw = by1 - by0;
    const float area = gw_raw * gh_raw;
    const float gcx = bx0 + 0.5f * gw_raw;
    const float gcy = by0 + 0.5f * gh_raw;
    const float gw = fmaxf(gw_raw, 1.0f);
    const float gh = fmaxf(gh_raw, 1.0f);

    const float TH  = (float)(1.0 / 9.0);
    const float SUB = (float)(0.5 / 9.0);
    const float PHI = (float)(1.0 - 0.0001);

    float att_sum = 0.0f;
    float rl_sum = 0.0f;
    float npf = 0.0f;

    // ---- Phase A: flags + regression for this thread's 2 anchors ----
    {
        const float4 anv[2] = {an0, an1};
        const bool   val[2] = {v0, v1};
        const int    aix[2] = {A0, A1};
        unsigned flg[2] = {0u, 0u};
#pragma unroll
        for (int k = 0; k < 2; ++k) {
            if (val[k]) {
                const float aw = anv[k].z - anv[k].x;
                const float ah = anv[k].w - anv[k].y;
                const float iw = fmaxf(fminf(anv[k].z, bx1) - fmaxf(anv[k].x, bx0), 0.0f);
                const float ih = fmaxf(fminf(anv[k].w, by1) - fmaxf(anv[k].y, by0), 0.0f);
                const float inter = iw * ih;
                const float uni = fmaxf(aw * ah + area - inter, 1e-8f);
                const float iou = inter / uni;
                const bool pos = (iou >= 0.5f);
                const bool neg = (iou < 0.4f);
                flg[k] = pos ? 2u : (neg ? 1u : 0u);
                if (pos) {
                    npf += 1.0f;
                    const float acx = anv[k].x + 0.5f * aw;
                    const float acy = anv[k].y + 0.5f * ah;
                    const float t0 = ((gcx - acx) / aw) / 0.1f;
                    const float t1 = ((gcy - acy) / ah) / 0.1f;
                    const float t2 = __logf(gw / aw) / 0.2f;
                    const float t3 = __logf(gh / ah) / 0.2f;
                    const float4 r = *reinterpret_cast<const float4*>(
                        regr + ((size_t)b * A_ANCH + aix[k]) * 4);
                    float d;
                    d = fabsf(t0 - r.x); rl_sum += (d <= TH) ? 4.5f * d * d : d - SUB;
                    d = fabsf(t1 - r.y); rl_sum += (d <= TH) ? 4.5f * d * d : d - SUB;
                    d = fabsf(t2 - r.z); rl_sum += (d <= TH) ? 4.5f * d * d : d - SUB;
                    d = fabsf(t3 - r.w); rl_sum += (d <= TH) ? 4.5f * d * d : d - SUB;
                }
            }
        }
        sFlag[tid]       = (unsigned char)flg[0];
        sFlag[tid + TPB] = (unsigned char)flg[1];
    }
    __syncthreads();

    // ---- Phase B: focal loss over this thread's 20 coalesced floats ----
#pragma unroll
    for (int j = 0; j < 5; ++j) {
        const int l0 = j * (TPB * 4) + tid * 4;          // local float index base
        const float pv[4] = {av[j].x, av[j].y, av[j].z, av[j].w};
#pragma unroll
        for (int d = 0; d < 4; ++d) {
            const int l = l0 + d;                        // 0..5119
            const int a = (l * 6554) >> 16;              // l / 10 (exact for l < 16389)
            const int c = l - a * 10;                    // l % 10
            const unsigned flag = sFlag[a];
            if (flag) {
                const float p = fminf(fmaxf(pv[d], 1e-4f), PHI);
                const bool t1 = (flag == 2u) && ((labmask >> c) & 1u);
                float loss;
                if (t1) {
                    const float q = 1.0f - p;
                    loss = 0.25f * q * q * (-__logf(p));
                } else {
                    loss = 0.75f * p * p * (-__logf(1.0f - p));
                }
                att_sum += loss;
            }
        }
    }

    // wave (64-lane) reduce
#pragma unroll
    for (int off = 32; off > 0; off >>= 1) {
        att_sum += __shfl_down(att_sum, off);
        rl_sum  += __shfl_down(rl_sum, off);
        npf     += __shfl_down(npf, off);
    }

    __shared__ float s_att[TPB / 64];
    __shared__ float s_rl[TPB / 64];
    __shared__ float s_np[TPB / 64];
    const int wave = tid >> 6;
    const int lane = tid & 63;
    if (lane == 0) { s_att[wave] = att_sum; s_rl[wave] = rl_sum; s_np[wave] = npf; }
    __syncthreads();
    if (tid == 0) {
        float a0s = 0.0f, r0 = 0.0f, n0 = 0.0f;
#pragma unroll
        for (int w = 0; w < TPB / 64; ++w) { a0s += s_att[w]; r0 += s_rl[w]; n0 += s_np[w]; }
        const int idx = b * NBX + blk;
        att_part[idx] = a0s;            // plain stores, no atomics
        rl_part[idx]  = r0;
        np_part[idx]  = n0;
    }
}

// One block, 8 waves: wave b tree-reduces image b's NBX partials.
__global__ __launch_bounds__(512) void focal_finalize(
    const float* __restrict__ att_part,
    const float* __restrict__ rl_part,
    const float* __restrict__ np_part,
    float* __restrict__ out)
{
    const int wave = threadIdx.x >> 6;
    const int lane = threadIdx.x & 63;
    float as = 0.0f, rs = 0.0f, ns = 0.0f;
    if (wave < B_IMG) {
        for (int i = lane; i < NBX; i += 64) {
            as += att_part[wave * NBX + i];
            rs += rl_part[wave * NBX + i];
            ns += np_part[wave * NBX + i];
        }
    }
#pragma unroll
    for (int off = 32; off > 0; off >>= 1) {
        as += __shfl_down(as, off);
        rs += __shfl_down(rs, off);
        ns += __shfl_down(ns, off);
    }
    __shared__ float sa[B_IMG], sr[B_IMG], sn[B_IMG];
    if (lane == 0 && wave < B_IMG) { sa[wave] = as; sr[wave] = rs; sn[wave] = ns; }
    __syncthreads();
    if (threadIdx.x == 0) {
        double am = 0.0, rm = 0.0;
        for (int b = 0; b < B_IMG; ++b) {
            const double npd = (double)sn[b];
            const double den = npd > 0.0 ? npd : 1.0;
            am += (double)sa[b] / den;
            if (npd > 0.0) rm += (double)sr[b] / (den * 4.0);
        }
        out[0] = (float)(am / (double)B_IMG);
        out[1] = (float)(rm / (double)B_IMG);
    }
}

extern "C" void kernel_launch(void* const* d_in, const int* in_sizes, int n_in,
                              void* d_out, int out_size, void* d_ws, size_t ws_size,
                              hipStream_t stream) {
    const float* attr = (const float*)d_in[0];   // attributes (B,A,C)
    const float* regr = (const float*)d_in[1];   // regressions (B,A,4)
    const float* anch = (const float*)d_in[2];   // anchors (1,A,4)
    const float* ann  = (const float*)d_in[3];   // annotations (B,14)
    float* out = (float*)d_out;

    float* att_part = (float*)d_ws;
    float* rl_part  = att_part + B_IMG * NBX;
    float* np_part  = rl_part + B_IMG * NBX;
    // All partials are written unconditionally every launch -> no memset needed.

    dim3 grid(NBX, B_IMG);
    focal_main<<<grid, TPB, 0, stream>>>(attr, regr, anch, ann, att_part, rl_part, np_part);
    focal_finalize<<<1, 512, 0, stream>>>(att_part, rl_part, np_part, out);
}